// Round 7
// baseline (122.959 us; speedup 1.0000x reference)
//
#include <hip/hip_runtime.h>

#define NB 8
#define NC 256
#define NN 1024

typedef unsigned short u16;
typedef unsigned int u32;
typedef __attribute__((ext_vector_type(8))) short short8;
typedef __attribute__((ext_vector_type(4))) float f32x4;

__device__ __forceinline__ u16 f2b(float f){ union{float ff;u32 i;}v; v.ff=f; u32 r=v.i+0x7FFFu+((v.i>>16)&1u); return (u16)(r>>16); }
__device__ __forceinline__ float b2f(u16 p){ union{u32 i;float f;}v; v.i=((u32)p)<<16; return v.f; }
__device__ __forceinline__ float pklo(u32 p){ union{u32 i;float f;}v; v.i=p<<16; return v.f; }
__device__ __forceinline__ float pkhi(u32 p){ union{u32 i;float f;}v; v.i=p&0xFFFF0000u; return v.f; }

// fold SCALE (1/sqrt(32)) * log2(e) into stored q so softmax is exp2(q'.k)
#define QSC 0.25503486f

union FR { uint4 u; short8 s; };

// K1: x[b,c,n] fp32 -> xt[b,n,c] bf16 (LDS tile transpose). grid (16,2,8).
__global__ void __launch_bounds__(256) k_cast(const float* __restrict__ x,
                                              u16* __restrict__ xt){
  const int n0 = blockIdx.x*64, c0 = blockIdx.y*128, b = blockIdx.z;
  const int tid = threadIdx.x;
  __shared__ u16 lt[64][136];
  #pragma unroll
  for (int cc = 0; cc < 4; cc++){
    const int c = c0 + cc*32 + (tid>>3);
    const int ns = (tid&7)*8;
    const float* src = x + ((size_t)(b*NC + c))*NN + n0 + ns;
    float4 a = *(const float4*)src;
    float4 d = *(const float4*)(src+4);
    const int cl = c - c0;
    lt[ns+0][cl] = f2b(a.x); lt[ns+1][cl] = f2b(a.y);
    lt[ns+2][cl] = f2b(a.z); lt[ns+3][cl] = f2b(a.w);
    lt[ns+4][cl] = f2b(d.x); lt[ns+5][cl] = f2b(d.y);
    lt[ns+6][cl] = f2b(d.z); lt[ns+7][cl] = f2b(d.w);
  }
  __syncthreads();
  #pragma unroll
  for (int p = 0; p < 4; p++){
    const int flat = p*256 + tid;
    const int row = flat >> 4, seg = flat & 15;
    uint4 d = *(uint4*)&lt[row][seg*8];
    *(uint4*)(xt + ((size_t)(b*NN + n0 + row))*NC + c0 + seg*8) = d;
  }
}

// K2: qkv = Wqkv @ x via MFMA, weight cast fused. 1-D grid 768:
// ot = bx>>5 (24), nb = bx&31 (nt = nb>>3, b = nb&7) -> XCD = b for all
// o-blocks sharing one xt tile (L2 locality).
__global__ void __launch_bounds__(256) k_qkv(const float* __restrict__ wq,
                                             const u16* __restrict__ xt,
                                             u16* __restrict__ qt,
                                             u16* __restrict__ kt,
                                             u16* __restrict__ v){
  const int ot = blockIdx.x >> 5, nb = blockIdx.x & 31;
  const int nt = nb >> 3, b = nb & 7;
  const int o0 = ot*32;
  const int tid = threadIdx.x, wv = tid>>6, lane = tid&63;
  const int l15 = lane&15, quad = lane>>4;
  const int n0w = nt*256 + wv*64;
  __shared__ u16 swq[32][264];
  __shared__ u16 s2[4][64][40];
  #pragma unroll
  for (int i = 0; i < 8; i++){                  // fp32 weights -> bf16 LDS
    const int flat = i*256 + tid;
    const int row = flat >> 6, c4 = flat & 63;
    float4 a = *(const float4*)(wq + (size_t)(o0+row)*NC + c4*4);
    uint2 p;
    p.x = (u32)f2b(a.x) | ((u32)f2b(a.y)<<16);
    p.y = (u32)f2b(a.z) | ((u32)f2b(a.w)<<16);
    *(uint2*)&swq[row][c4*4] = p;
  }
  __syncthreads();
  f32x4 acc[2][4];
  #pragma unroll
  for (int mt = 0; mt < 2; mt++)
    #pragma unroll
    for (int nt2 = 0; nt2 < 4; nt2++) acc[mt][nt2] = (f32x4){0.f,0.f,0.f,0.f};
  const u16* xb = xt + ((size_t)(b*NN + n0w))*NC;
  for (int k0 = 0; k0 < 256; k0 += 32){
    FR af[2], bf[4];
    af[0].u = *(uint4*)&swq[l15][k0 + quad*8];
    af[1].u = *(uint4*)&swq[16+l15][k0 + quad*8];
    #pragma unroll
    for (int nt2 = 0; nt2 < 4; nt2++)
      bf[nt2].u = *(const uint4*)(xb + (size_t)(nt2*16+l15)*NC + k0 + quad*8);
    #pragma unroll
    for (int mt = 0; mt < 2; mt++)
      #pragma unroll
      for (int nt2 = 0; nt2 < 4; nt2++)
        acc[mt][nt2] = __builtin_amdgcn_mfma_f32_16x16x32_bf16(af[mt].s, bf[nt2].s, acc[mt][nt2], 0,0,0);
  }
  if (ot < 16){                       // q/k: repack D (row=o,col=n) -> [n][o]
    const float sc = (ot < 8) ? QSC : 1.0f;
    u16* dstbase = (ot < 8) ? qt : kt;
    const int h = (ot < 8) ? ot : ot-8;
    #pragma unroll
    for (int mt = 0; mt < 2; mt++)
      #pragma unroll
      for (int nt2 = 0; nt2 < 4; nt2++){
        uint2 w;
        w.x = (u32)f2b(acc[mt][nt2][0]*sc) | ((u32)f2b(acc[mt][nt2][1]*sc)<<16);
        w.y = (u32)f2b(acc[mt][nt2][2]*sc) | ((u32)f2b(acc[mt][nt2][3]*sc)<<16);
        *(uint2*)&s2[wv][nt2*16+l15][mt*16+quad*4] = w;
      }
    __syncthreads();
    u16* db = dstbase + ((size_t)(b*8+h)*NN + n0w)*32;
    #pragma unroll
    for (int p = 0; p < 4; p++){
      const int n_loc = p*16 + (lane>>2), seg = lane&3;
      uint4 d = *(uint4*)&s2[wv][n_loc][seg*8];
      *(uint4*)(db + (size_t)n_loc*32 + seg*8) = d;
    }
  } else {                            // v: direct [c][n] scalar stores
    const int c0 = o0 - 512;
    #pragma unroll
    for (int mt = 0; mt < 2; mt++)
      #pragma unroll
      for (int nt2 = 0; nt2 < 4; nt2++)
        #pragma unroll
        for (int r = 0; r < 4; r++)
          v[(size_t)(b*NC + c0 + mt*16 + quad*4 + r)*NN + n0w + nt2*16 + l15] = f2b(acc[mt][nt2][r]);
  }
}

// K3: MFMA flash attention + fused LePE, software-pipelined.
// 1-D grid 512: cq = bx>>6 (q-chunk), bh = bx&63 -> XCD = h; all q-chunks and
// batches of head h share K/V in one XCD's L2.
// P-tile LDS double-buffered; K/V frags prefetched one chunk ahead.
__global__ void __launch_bounds__(256) k_attn(const u16* __restrict__ qt,
                                              const u16* __restrict__ kt,
                                              const u16* __restrict__ v,
                                              const float* __restrict__ lw,
                                              const float* __restrict__ lb,
                                              u16* __restrict__ tt){
  const int cq = blockIdx.x >> 6, bh = blockIdx.x & 63;
  const int b = bh >> 3, h = bh & 7;
  const int tid = threadIdx.x;
  const int wv = tid >> 6, lane = tid & 63;
  const int l15 = lane & 15, quad = lane >> 4;
  const int q0 = (cq*4 + wv)*32;

  __shared__ u16 pb[4][2][2][16][40];  // [wave][buf][AB][q][key]
  __shared__ u16 vstage[8][32][38];    // LePE halo [row][c][col]
  __shared__ u16 s_out[4][32][36];     // attn out tile [q][c]

  // --- stage LePE halo: rows cq*4-2 .. cq*4+5 of v for this head's channels
  {
    const int rr = tid >> 5, lc2 = tid & 31;
    const int yy = cq*4 - 2 + rr;
    u32* dst32 = (u32*)&vstage[rr][lc2][0];
    if (yy < 0 || yy > 31){
      #pragma unroll
      for (int j = 0; j < 19; j++) dst32[j] = 0;
    } else {
      const u16* src = v + ((size_t)(b*NC + h*32 + lc2))*NN + yy*32;
      uint4 a = *(const uint4*)src;
      uint4 b4 = *(const uint4*)(src+8);
      uint4 c4 = *(const uint4*)(src+16);
      uint4 d4 = *(const uint4*)(src+24);
      dst32[0] = 0;
      dst32[1]=a.x;  dst32[2]=a.y;  dst32[3]=a.z;  dst32[4]=a.w;
      dst32[5]=b4.x; dst32[6]=b4.y; dst32[7]=b4.z; dst32[8]=b4.w;
      dst32[9]=c4.x; dst32[10]=c4.y; dst32[11]=c4.z; dst32[12]=c4.w;
      dst32[13]=d4.x; dst32[14]=d4.y; dst32[15]=d4.z; dst32[16]=d4.w;
      dst32[17]=0; dst32[18]=0;
    }
  }
  __syncthreads();

  const u16* qtb = qt + (size_t)bh*NN*32;
  const u16* ktb = kt + (size_t)bh*NN*32;
  const u16* vbp = v + (size_t)(b*256 + h*32)*NN;

  FR qa, qb_;
  qa.u  = *(const uint4*)(qtb + (size_t)(q0      + l15)*32 + quad*8);
  qb_.u = *(const uint4*)(qtb + (size_t)(q0 + 16 + l15)*32 + quad*8);

  f32x4 z = {0.f,0.f,0.f,0.f};
  f32x4 oA0 = z, oA1 = z, oB0 = z, oB1 = z;
  float denA[4] = {0.f,0.f,0.f,0.f}, denB[4] = {0.f,0.f,0.f,0.f};

  FR kc0, kc1, vc0, vc1;               // current chunk frags
  kc0.u = *(const uint4*)(ktb + (size_t)(l15     )*32 + quad*8);
  kc1.u = *(const uint4*)(ktb + (size_t)(16 + l15)*32 + quad*8);
  vc0.u = *(const uint4*)(vbp + (size_t)(l15     )*NN + quad*8);
  vc1.u = *(const uint4*)(vbp + (size_t)(16 + l15)*NN + quad*8);

  // chunk 0: QK -> exp -> pack into pb[wv][0]
  {
    f32x4 sA0 = __builtin_amdgcn_mfma_f32_16x16x32_bf16(qa.s,  kc0.s, z, 0,0,0);
    f32x4 sA1 = __builtin_amdgcn_mfma_f32_16x16x32_bf16(qa.s,  kc1.s, z, 0,0,0);
    f32x4 sB0 = __builtin_amdgcn_mfma_f32_16x16x32_bf16(qb_.s, kc0.s, z, 0,0,0);
    f32x4 sB1 = __builtin_amdgcn_mfma_f32_16x16x32_bf16(qb_.s, kc1.s, z, 0,0,0);
    u16* pA = &pb[wv][0][0][0][0];
    u16* pB = &pb[wv][0][1][0][0];
    #pragma unroll
    for (int r = 0; r < 4; r++){
      float pA0 = __builtin_amdgcn_exp2f(sA0[r]);
      float pA1 = __builtin_amdgcn_exp2f(sA1[r]);
      float pB0 = __builtin_amdgcn_exp2f(sB0[r]);
      float pB1 = __builtin_amdgcn_exp2f(sB1[r]);
      denA[r] += pA0 + pA1;
      denB[r] += pB0 + pB1;
      const int row = (quad*4 + r)*40;
      pA[row + l15]      = (u16)(__float_as_uint(pA0)>>16);
      pA[row + 16 + l15] = (u16)(__float_as_uint(pA1)>>16);
      pB[row + l15]      = (u16)(__float_as_uint(pB0)>>16);
      pB[row + 16 + l15] = (u16)(__float_as_uint(pB1)>>16);
    }
  }

  for (int it = 1; it < 32; it++){
    const int m0 = it*32;
    FR kn0, kn1, vn0, vn1;             // prefetch next chunk
    kn0.u = *(const uint4*)(ktb + (size_t)(m0      + l15)*32 + quad*8);
    kn1.u = *(const uint4*)(ktb + (size_t)(m0 + 16 + l15)*32 + quad*8);
    vn0.u = *(const uint4*)(vbp + (size_t)(l15     )*NN + m0 + quad*8);
    vn1.u = *(const uint4*)(vbp + (size_t)(16 + l15)*NN + m0 + quad*8);

    // PV for chunk it-1 (P from LDS buf (it-1)&1, V from current regs)
    {
      const u16* pbr = &pb[wv][(it-1)&1][0][0][0];
      FR pfA, pfB;
      pfA.u = *(const uint4*)(pbr + l15*40 + quad*8);
      pfB.u = *(const uint4*)(pbr + 640 + l15*40 + quad*8);
      oA0 = __builtin_amdgcn_mfma_f32_16x16x32_bf16(pfA.s, vc0.s, oA0, 0,0,0);
      oA1 = __builtin_amdgcn_mfma_f32_16x16x32_bf16(pfA.s, vc1.s, oA1, 0,0,0);
      oB0 = __builtin_amdgcn_mfma_f32_16x16x32_bf16(pfB.s, vc0.s, oB0, 0,0,0);
      oB1 = __builtin_amdgcn_mfma_f32_16x16x32_bf16(pfB.s, vc1.s, oB1, 0,0,0);
    }
    // QK for chunk it (frags just prefetched)
    {
      f32x4 sA0 = __builtin_amdgcn_mfma_f32_16x16x32_bf16(qa.s,  kn0.s, z, 0,0,0);
      f32x4 sA1 = __builtin_amdgcn_mfma_f32_16x16x32_bf16(qa.s,  kn1.s, z, 0,0,0);
      f32x4 sB0 = __builtin_amdgcn_mfma_f32_16x16x32_bf16(qb_.s, kn0.s, z, 0,0,0);
      f32x4 sB1 = __builtin_amdgcn_mfma_f32_16x16x32_bf16(qb_.s, kn1.s, z, 0,0,0);
      u16* pA = &pb[wv][it&1][0][0][0];
      u16* pB = &pb[wv][it&1][1][0][0];
      #pragma unroll
      for (int r = 0; r < 4; r++){
        float pA0 = __builtin_amdgcn_exp2f(sA0[r]);
        float pA1 = __builtin_amdgcn_exp2f(sA1[r]);
        float pB0 = __builtin_amdgcn_exp2f(sB0[r]);
        float pB1 = __builtin_amdgcn_exp2f(sB1[r]);
        denA[r] += pA0 + pA1;
        denB[r] += pB0 + pB1;
        const int row = (quad*4 + r)*40;
        pA[row + l15]      = (u16)(__float_as_uint(pA0)>>16);
        pA[row + 16 + l15] = (u16)(__float_as_uint(pA1)>>16);
        pB[row + l15]      = (u16)(__float_as_uint(pB0)>>16);
        pB[row + 16 + l15] = (u16)(__float_as_uint(pB1)>>16);
      }
    }
    kc0 = kn0; kc1 = kn1; vc0 = vn0; vc1 = vn1;
  }
  // epilogue PV for chunk 31 (buf 1)
  {
    const u16* pbr = &pb[wv][1][0][0][0];
    FR pfA, pfB;
    pfA.u = *(const uint4*)(pbr + l15*40 + quad*8);
    pfB.u = *(const uint4*)(pbr + 640 + l15*40 + quad*8);
    oA0 = __builtin_amdgcn_mfma_f32_16x16x32_bf16(pfA.s, vc0.s, oA0, 0,0,0);
    oA1 = __builtin_amdgcn_mfma_f32_16x16x32_bf16(pfA.s, vc1.s, oA1, 0,0,0);
    oB0 = __builtin_amdgcn_mfma_f32_16x16x32_bf16(pfB.s, vc0.s, oB0, 0,0,0);
    oB1 = __builtin_amdgcn_mfma_f32_16x16x32_bf16(pfB.s, vc1.s, oB1, 0,0,0);
  }

  #pragma unroll
  for (int r = 0; r < 4; r++){
    #pragma unroll
    for (int m = 1; m < 16; m <<= 1){
      denA[r] += __shfl_xor(denA[r], m);
      denB[r] += __shfl_xor(denB[r], m);
    }
  }
  // stage normalized attn out (bf16) in s_out[q][c]
  {
    u16* so = &s_out[wv][0][0];
    #pragma unroll
    for (int r = 0; r < 4; r++){
      const int q = quad*4 + r;
      const float iA = 1.f/denA[r], iB = 1.f/denB[r];
      so[q*36 + l15]           = f2b(oA0[r]*iA);
      so[q*36 + 16 + l15]      = f2b(oA1[r]*iA);
      so[(q+16)*36 + l15]      = f2b(oB0[r]*iB);
      so[(q+16)*36 + 16 + l15] = f2b(oB1[r]*iB);
    }
  }
  // LePE per lane: channel lc, 16 x-positions of image row (q0/32)
  {
    const int lc = lane & 31, qh = lane >> 5;
    float lep[16];
    const float lbias = lb[h*32 + lc];
    #pragma unroll
    for (int i = 0; i < 16; i++) lep[i] = lbias;
    const float* lwc = lw + (size_t)(h*32 + lc)*25;
    #pragma unroll
    for (int ky = 0; ky < 5; ky++){
      const u32* vr = (const u32*)&vstage[wv + ky][lc][0];
      float vv[20];
      #pragma unroll
      for (int jj = 0; jj < 10; jj++){
        u32 pk = vr[qh*8 + jj];
        vv[2*jj]   = pklo(pk);
        vv[2*jj+1] = pkhi(pk);
      }
      const float w0 = lwc[ky*5+0], w1 = lwc[ky*5+1], w2 = lwc[ky*5+2],
                  w3 = lwc[ky*5+3], w4 = lwc[ky*5+4];
      #pragma unroll
      for (int i = 0; i < 16; i++)
        lep[i] += w0*vv[i] + w1*vv[i+1] + w2*vv[i+2] + w3*vv[i+3] + w4*vv[i+4];
    }
    u16* tb = tt + ((size_t)(b*NN + q0))*NC + h*32;
    const u16* so = &s_out[wv][0][0];
    #pragma unroll
    for (int i = 0; i < 16; i++){
      const int q = qh*16 + i;
      tb[(size_t)q*NC + lc] = f2b(b2f(so[q*36 + lc]) + lep[i]);
    }
  }
}

// K4: out = Wp @ t + bias via MFMA, weight cast fused. 1-D grid 512:
// ot = bx>>6 (8), rest = bx&63 (nt = rest>>3 of 128 n, b = rest&7) -> XCD = b.
__global__ void __launch_bounds__(256) k_proj(const float* __restrict__ wp,
                                              const u16* __restrict__ tt,
                                              const float* __restrict__ pbias,
                                              float* __restrict__ out){
  const int ot = blockIdx.x >> 6, rest = blockIdx.x & 63;
  const int nt = rest >> 3, b = rest & 7;
  const int o0 = ot*32;
  const int tid = threadIdx.x, wv = tid>>6, lane = tid&63;
  const int l15 = lane&15, quad = lane>>4;
  const int n0w = nt*128 + wv*32;
  __shared__ u16 swp[32][264];
  #pragma unroll
  for (int i = 0; i < 8; i++){                  // fp32 weights -> bf16 LDS
    const int flat = i*256 + tid;
    const int row = flat >> 6, c4 = flat & 63;
    float4 a = *(const float4*)(wp + (size_t)(o0+row)*NC + c4*4);
    uint2 p;
    p.x = (u32)f2b(a.x) | ((u32)f2b(a.y)<<16);
    p.y = (u32)f2b(a.z) | ((u32)f2b(a.w)<<16);
    *(uint2*)&swp[row][c4*4] = p;
  }
  __syncthreads();
  f32x4 acc[2][2];
  #pragma unroll
  for (int mt = 0; mt < 2; mt++)
    #pragma unroll
    for (int n2 = 0; n2 < 2; n2++) acc[mt][n2] = (f32x4){0.f,0.f,0.f,0.f};
  const u16* tb = tt + ((size_t)(b*NN + n0w))*NC;
  for (int k0 = 0; k0 < 256; k0 += 32){
    FR af[2], bf[2];
    af[0].u = *(uint4*)&swp[l15][k0 + quad*8];
    af[1].u = *(uint4*)&swp[16+l15][k0 + quad*8];
    bf[0].u = *(const uint4*)(tb + (size_t)(l15     )*NC + k0 + quad*8);
    bf[1].u = *(const uint4*)(tb + (size_t)(16 + l15)*NC + k0 + quad*8);
    #pragma unroll
    for (int mt = 0; mt < 2; mt++)
      #pragma unroll
      for (int n2 = 0; n2 < 2; n2++)
        acc[mt][n2] = __builtin_amdgcn_mfma_f32_16x16x32_bf16(af[mt].s, bf[n2].s, acc[mt][n2], 0,0,0);
  }
  float bv[2][4];
  #pragma unroll
  for (int mt = 0; mt < 2; mt++)
    #pragma unroll
    for (int r = 0; r < 4; r++) bv[mt][r] = pbias[o0 + mt*16 + quad*4 + r];
  #pragma unroll
  for (int mt = 0; mt < 2; mt++)
    #pragma unroll
    for (int n2 = 0; n2 < 2; n2++)
      #pragma unroll
      for (int r = 0; r < 4; r++)
        out[(size_t)(b*NC + o0 + mt*16 + quad*4 + r)*NN + n0w + n2*16 + l15] = acc[mt][n2][r] + bv[mt][r];
}

extern "C" void kernel_launch(void* const* d_in, const int* in_sizes, int n_in,
                              void* d_out, int out_size, void* d_ws, size_t ws_size,
                              hipStream_t stream){
  const float* x      = (const float*)d_in[0];
  const float* qkv_w  = (const float*)d_in[1];
  const float* proj_w = (const float*)d_in[2];
  const float* proj_b = (const float*)d_in[3];
  const float* lepe_w = (const float*)d_in[4];
  const float* lepe_b = (const float*)d_in[5];
  float* out = (float*)d_out;

  // ws (u16 units): xt 2M | qt 2M | kt 2M | v 2M | tt 2M  (20 MB)
  if (ws_size < (size_t)20*1024*1024) return;
  u16* xt = (u16*)d_ws;
  u16* qt = xt + 2097152;
  u16* kt = qt + 2097152;
  u16* v  = kt + 2097152;
  u16* tt = v  + 2097152;

  k_cast<<<dim3(16, 2, 8), 256, 0, stream>>>(x, xt);
  k_qkv <<<dim3(768),      256, 0, stream>>>(qkv_w, xt, qt, kt, v);
  k_attn<<<dim3(512),      256, 0, stream>>>(qt, kt, v, lepe_w, lepe_b, tt);
  k_proj<<<dim3(512),      256, 0, stream>>>(proj_w, tt, proj_b, out);
}

// Round 8
// 122.707 us; speedup vs baseline: 1.0021x; 1.0021x over previous
//
#include <hip/hip_runtime.h>

#define NB 8
#define NC 256
#define NN 1024

typedef unsigned short u16;
typedef unsigned int u32;
typedef __attribute__((ext_vector_type(8))) short short8;
typedef __attribute__((ext_vector_type(4))) float f32x4;

__device__ __forceinline__ u16 f2b(float f){ union{float ff;u32 i;}v; v.ff=f; u32 r=v.i+0x7FFFu+((v.i>>16)&1u); return (u16)(r>>16); }
__device__ __forceinline__ float b2f(u16 p){ union{u32 i;float f;}v; v.i=((u32)p)<<16; return v.f; }
__device__ __forceinline__ float pklo(u32 p){ union{u32 i;float f;}v; v.i=p<<16; return v.f; }
__device__ __forceinline__ float pkhi(u32 p){ union{u32 i;float f;}v; v.i=p&0xFFFF0000u; return v.f; }

// fold SCALE (1/sqrt(32)) * log2(e) into stored q so softmax is exp2(q'.k)
#define QSC 0.25503486f

union FR { uint4 u; short8 s; };

// K1: x[b,c,n] fp32 -> xt[b,n,c] bf16 (LDS tile transpose). grid (16,2,8).
__global__ void __launch_bounds__(256) k_cast(const float* __restrict__ x,
                                              u16* __restrict__ xt){
  const int n0 = blockIdx.x*64, c0 = blockIdx.y*128, b = blockIdx.z;
  const int tid = threadIdx.x;
  __shared__ u16 lt[64][136];
  #pragma unroll
  for (int cc = 0; cc < 4; cc++){
    const int c = c0 + cc*32 + (tid>>3);
    const int ns = (tid&7)*8;
    const float* src = x + ((size_t)(b*NC + c))*NN + n0 + ns;
    float4 a = *(const float4*)src;
    float4 d = *(const float4*)(src+4);
    const int cl = c - c0;
    lt[ns+0][cl] = f2b(a.x); lt[ns+1][cl] = f2b(a.y);
    lt[ns+2][cl] = f2b(a.z); lt[ns+3][cl] = f2b(a.w);
    lt[ns+4][cl] = f2b(d.x); lt[ns+5][cl] = f2b(d.y);
    lt[ns+6][cl] = f2b(d.z); lt[ns+7][cl] = f2b(d.w);
  }
  __syncthreads();
  #pragma unroll
  for (int p = 0; p < 4; p++){
    const int flat = p*256 + tid;
    const int row = flat >> 4, seg = flat & 15;
    uint4 d = *(uint4*)&lt[row][seg*8];
    *(uint4*)(xt + ((size_t)(b*NN + n0 + row))*NC + c0 + seg*8) = d;
  }
}

// K2: qkv = Wqkv @ x via MFMA, 64o x 128n per block (halved xt L2 traffic).
// 1-D grid 768: ot = bx>>6 (12), nt = (bx&63)>>3, b = bx&7 (XCD = b).
// LDS 52 KB -> 3 blocks/CU, 768 = full single-round residency.
//   ot 0-3: q -> qt[b,h][n][32] (x QSC)   ot 4-7: k -> kt   ot 8-11: v -> v[b,c][n]
__global__ void __launch_bounds__(256) k_qkv(const float* __restrict__ wq,
                                             const u16* __restrict__ xt,
                                             u16* __restrict__ qt,
                                             u16* __restrict__ kt,
                                             u16* __restrict__ v){
  const int ot = blockIdx.x >> 6, rest = blockIdx.x & 63;
  const int nt = rest >> 3, b = rest & 7;
  const int o0 = ot*64;
  const int tid = threadIdx.x, wv = tid>>6, lane = tid&63;
  const int l15 = lane&15, quad = lane>>4;
  const int n0w = nt*128 + wv*32;
  __shared__ u16 swq[64][264];
  __shared__ u16 s2[4][32][72];
  #pragma unroll
  for (int i = 0; i < 16; i++){                 // fp32 weights -> bf16 LDS
    const int flat = i*256 + tid;
    const int row = flat >> 6, c4 = flat & 63;
    float4 a = *(const float4*)(wq + (size_t)(o0+row)*NC + c4*4);
    uint2 p;
    p.x = (u32)f2b(a.x) | ((u32)f2b(a.y)<<16);
    p.y = (u32)f2b(a.z) | ((u32)f2b(a.w)<<16);
    *(uint2*)&swq[row][c4*4] = p;
  }
  __syncthreads();
  f32x4 acc[4][2];
  #pragma unroll
  for (int mt = 0; mt < 4; mt++)
    #pragma unroll
    for (int n2 = 0; n2 < 2; n2++) acc[mt][n2] = (f32x4){0.f,0.f,0.f,0.f};
  const u16* xb = xt + ((size_t)(b*NN + n0w))*NC;
  for (int k0 = 0; k0 < 256; k0 += 32){
    FR af[4], bf[2];
    #pragma unroll
    for (int mt = 0; mt < 4; mt++)
      af[mt].u = *(uint4*)&swq[mt*16 + l15][k0 + quad*8];
    #pragma unroll
    for (int n2 = 0; n2 < 2; n2++)
      bf[n2].u = *(const uint4*)(xb + (size_t)(n2*16+l15)*NC + k0 + quad*8);
    #pragma unroll
    for (int mt = 0; mt < 4; mt++)
      #pragma unroll
      for (int n2 = 0; n2 < 2; n2++)
        acc[mt][n2] = __builtin_amdgcn_mfma_f32_16x16x32_bf16(af[mt].s, bf[n2].s, acc[mt][n2], 0,0,0);
  }
  if (ot < 8){                        // q/k: repack D (row=o,col=n) -> [n][o]
    const float sc = (ot < 4) ? QSC : 1.0f;
    u16* dstbase = (ot < 4) ? qt : kt;
    const int h0 = (ot < 4) ? (o0 >> 5) : ((o0-256) >> 5);
    #pragma unroll
    for (int mt = 0; mt < 4; mt++)
      #pragma unroll
      for (int n2 = 0; n2 < 2; n2++){
        uint2 w;
        w.x = (u32)f2b(acc[mt][n2][0]*sc) | ((u32)f2b(acc[mt][n2][1]*sc)<<16);
        w.y = (u32)f2b(acc[mt][n2][2]*sc) | ((u32)f2b(acc[mt][n2][3]*sc)<<16);
        *(uint2*)&s2[wv][n2*16+l15][mt*16+quad*4] = w;
      }
    __syncthreads();
    #pragma unroll
    for (int p = 0; p < 4; p++){
      const int u = p*64 + lane;
      const int hh = u >> 7, rem = u & 127;
      const int n_loc = rem >> 2, seg = rem & 3;
      uint4 d = *(uint4*)&s2[wv][n_loc][hh*32 + seg*8];
      u16* db = dstbase + ((size_t)(b*8 + h0 + hh)*NN + n0w + n_loc)*32 + seg*8;
      *(uint4*)db = d;
    }
  } else {                            // v: direct [c][n] scalar stores
    const int c0 = o0 - 512;
    #pragma unroll
    for (int mt = 0; mt < 4; mt++)
      #pragma unroll
      for (int n2 = 0; n2 < 2; n2++)
        #pragma unroll
        for (int r = 0; r < 4; r++)
          v[(size_t)(b*NC + c0 + mt*16 + quad*4 + r)*NN + n0w + n2*16 + l15] = f2b(acc[mt][n2][r]);
  }
}

// K3: MFMA flash attention + fused LePE, 2-way KEY-SPLIT for TLP.
// 1-D grid 1024: qt2 = bx>>6 (16 chunks of 64 q), bh = bx&63 (XCD = h).
// Block = 4 waves: wave wv -> qg = wv&1 (32-q group), kh = wv>>1 (512-key half).
// kh=1 waves dump partial (num,den) to LDS; kh=0 waves merge + LePE + store.
// LDS 38 KB -> 4 blocks/CU = 16 waves/CU (2x R7 TLP).
__global__ void __launch_bounds__(256, 4) k_attn(const u16* __restrict__ qt,
                                                 const u16* __restrict__ kt,
                                                 const u16* __restrict__ v,
                                                 const float* __restrict__ lw,
                                                 const float* __restrict__ lb,
                                                 u16* __restrict__ tt){
  const int qt2 = blockIdx.x >> 6, bh = blockIdx.x & 63;
  const int b = bh >> 3, h = bh & 7;
  const int tid = threadIdx.x;
  const int wv = tid >> 6, lane = tid & 63;
  const int l15 = lane & 15, quad = lane >> 4;
  const int qg = wv & 1, kh = wv >> 1;
  const int q0 = qt2*64 + qg*32;

  __shared__ u16 pb[4][2][16][40];     // per-wave P tile [wave][AB][q][key]
  __shared__ u16 vstage[6][32][38];    // LePE halo rows qt2*2-2 .. qt2*2+3
  __shared__ u16 s_out[2][32][36];     // attn out [qg][q][c]
  __shared__ float mnum[2][32][33];    // key-split merge: numerator partials
  __shared__ float mden[2][32];        // key-split merge: denominator partials

  // --- stage LePE halo (6 rows x 32 ch)
  {
    const int rr = tid >> 5, lc2 = tid & 31;
    if (rr < 6){
      const int yy = qt2*2 - 2 + rr;
      u32* dst32 = (u32*)&vstage[rr][lc2][0];
      if (yy < 0 || yy > 31){
        #pragma unroll
        for (int j = 0; j < 19; j++) dst32[j] = 0;
      } else {
        const u16* src = v + ((size_t)(b*NC + h*32 + lc2))*NN + yy*32;
        uint4 a = *(const uint4*)src;
        uint4 b4 = *(const uint4*)(src+8);
        uint4 c4 = *(const uint4*)(src+16);
        uint4 d4 = *(const uint4*)(src+24);
        dst32[0] = 0;
        dst32[1]=a.x;  dst32[2]=a.y;  dst32[3]=a.z;  dst32[4]=a.w;
        dst32[5]=b4.x; dst32[6]=b4.y; dst32[7]=b4.z; dst32[8]=b4.w;
        dst32[9]=c4.x; dst32[10]=c4.y; dst32[11]=c4.z; dst32[12]=c4.w;
        dst32[13]=d4.x; dst32[14]=d4.y; dst32[15]=d4.z; dst32[16]=d4.w;
        dst32[17]=0; dst32[18]=0;
      }
    }
  }
  __syncthreads();

  const u16* qtb = qt + (size_t)bh*NN*32;
  const u16* ktb = kt + (size_t)bh*NN*32;
  const u16* vbp = v + (size_t)(b*256 + h*32)*NN;

  FR qa, qb_;
  qa.u  = *(const uint4*)(qtb + (size_t)(q0      + l15)*32 + quad*8);
  qb_.u = *(const uint4*)(qtb + (size_t)(q0 + 16 + l15)*32 + quad*8);

  f32x4 z = {0.f,0.f,0.f,0.f};
  f32x4 oA0 = z, oA1 = z, oB0 = z, oB1 = z;
  float denA[4] = {0.f,0.f,0.f,0.f}, denB[4] = {0.f,0.f,0.f,0.f};

  u16* pA = &pb[wv][0][0][0];
  u16* pB = &pb[wv][1][0][0];

  for (int it = 0; it < 16; it++){
    const int m0 = kh*512 + it*32;
    FR kf0, kf1, vf0, vf1;
    kf0.u = *(const uint4*)(ktb + (size_t)(m0      + l15)*32 + quad*8);
    kf1.u = *(const uint4*)(ktb + (size_t)(m0 + 16 + l15)*32 + quad*8);
    vf0.u = *(const uint4*)(vbp + (size_t)(l15     )*NN + m0 + quad*8);
    vf1.u = *(const uint4*)(vbp + (size_t)(16 + l15)*NN + m0 + quad*8);

    f32x4 sA0 = __builtin_amdgcn_mfma_f32_16x16x32_bf16(qa.s,  kf0.s, z, 0,0,0);
    f32x4 sA1 = __builtin_amdgcn_mfma_f32_16x16x32_bf16(qa.s,  kf1.s, z, 0,0,0);
    f32x4 sB0 = __builtin_amdgcn_mfma_f32_16x16x32_bf16(qb_.s, kf0.s, z, 0,0,0);
    f32x4 sB1 = __builtin_amdgcn_mfma_f32_16x16x32_bf16(qb_.s, kf1.s, z, 0,0,0);

    #pragma unroll
    for (int r = 0; r < 4; r++){
      float pA0 = __builtin_amdgcn_exp2f(sA0[r]);
      float pA1 = __builtin_amdgcn_exp2f(sA1[r]);
      float pB0 = __builtin_amdgcn_exp2f(sB0[r]);
      float pB1 = __builtin_amdgcn_exp2f(sB1[r]);
      denA[r] += pA0 + pA1;
      denB[r] += pB0 + pB1;
      const int row = (quad*4 + r)*40;
      pA[row + l15]      = (u16)(__float_as_uint(pA0)>>16);
      pA[row + 16 + l15] = (u16)(__float_as_uint(pA1)>>16);
      pB[row + l15]      = (u16)(__float_as_uint(pB0)>>16);
      pB[row + 16 + l15] = (u16)(__float_as_uint(pB1)>>16);
    }
    FR pfA, pfB;                        // D-layout -> A-layout via LDS (per-wave)
    pfA.u = *(const uint4*)(pA + l15*40 + quad*8);
    pfB.u = *(const uint4*)(pB + l15*40 + quad*8);

    oA0 = __builtin_amdgcn_mfma_f32_16x16x32_bf16(pfA.s, vf0.s, oA0, 0,0,0);
    oA1 = __builtin_amdgcn_mfma_f32_16x16x32_bf16(pfA.s, vf1.s, oA1, 0,0,0);
    oB0 = __builtin_amdgcn_mfma_f32_16x16x32_bf16(pfB.s, vf0.s, oB0, 0,0,0);
    oB1 = __builtin_amdgcn_mfma_f32_16x16x32_bf16(pfB.s, vf1.s, oB1, 0,0,0);
  }
  #pragma unroll
  for (int r = 0; r < 4; r++){          // 16-lane reduce within quad-row
    #pragma unroll
    for (int m = 1; m < 16; m <<= 1){
      denA[r] += __shfl_xor(denA[r], m);
      denB[r] += __shfl_xor(denB[r], m);
    }
  }
  __syncthreads();
  if (kh == 1){                         // dump partials
    #pragma unroll
    for (int r = 0; r < 4; r++){
      mnum[qg][quad*4 + r][l15]          = oA0[r];
      mnum[qg][quad*4 + r][16 + l15]     = oA1[r];
      mnum[qg][16 + quad*4 + r][l15]     = oB0[r];
      mnum[qg][16 + quad*4 + r][16 + l15]= oB1[r];
    }
    if (l15 == 0){
      #pragma unroll
      for (int r = 0; r < 4; r++){
        mden[qg][quad*4 + r]      = denA[r];
        mden[qg][16 + quad*4 + r] = denB[r];
      }
    }
  }
  __syncthreads();
  if (kh == 0){
    // merge halves, normalize -> s_out[qg]
    u16* so = &s_out[qg][0][0];
    #pragma unroll
    for (int r = 0; r < 4; r++){
      const int q = quad*4 + r;
      const float dA = denA[r] + mden[qg][q];
      const float dB = denB[r] + mden[qg][16 + q];
      const float iA = 1.f/dA, iB = 1.f/dB;
      so[q*36 + l15]           = f2b((oA0[r] + mnum[qg][q][l15])*iA);
      so[q*36 + 16 + l15]      = f2b((oA1[r] + mnum[qg][q][16+l15])*iA);
      so[(q+16)*36 + l15]      = f2b((oB0[r] + mnum[qg][16+q][l15])*iB);
      so[(q+16)*36 + 16 + l15] = f2b((oB1[r] + mnum[qg][16+q][16+l15])*iB);
    }
    // LePE per lane: channel lc, 16 x-positions of image row y = qt2*2+qg
    const int lc = lane & 31, qh = lane >> 5;
    float lep[16];
    const float lbias = lb[h*32 + lc];
    #pragma unroll
    for (int i = 0; i < 16; i++) lep[i] = lbias;
    const float* lwc = lw + (size_t)(h*32 + lc)*25;
    #pragma unroll
    for (int ky = 0; ky < 5; ky++){
      const u32* vr = (const u32*)&vstage[qg + ky][lc][0];
      float vv[20];
      #pragma unroll
      for (int jj = 0; jj < 10; jj++){
        u32 pk = vr[qh*8 + jj];
        vv[2*jj]   = pklo(pk);
        vv[2*jj+1] = pkhi(pk);
      }
      const float w0 = lwc[ky*5+0], w1 = lwc[ky*5+1], w2 = lwc[ky*5+2],
                  w3 = lwc[ky*5+3], w4 = lwc[ky*5+4];
      #pragma unroll
      for (int i = 0; i < 16; i++)
        lep[i] += w0*vv[i] + w1*vv[i+1] + w2*vv[i+2] + w3*vv[i+3] + w4*vv[i+4];
    }
    u16* tb = tt + ((size_t)(b*NN + q0))*NC + h*32;
    #pragma unroll
    for (int i = 0; i < 16; i++){
      const int q = qh*16 + i;
      tb[(size_t)q*NC + lc] = f2b(b2f(so[q*36 + lc]) + lep[i]);
    }
  }
}

// K4: out = Wp @ t + bias via MFMA, weight cast fused. 1-D grid 512 (XCD = b).
__global__ void __launch_bounds__(256) k_proj(const float* __restrict__ wp,
                                              const u16* __restrict__ tt,
                                              const float* __restrict__ pbias,
                                              float* __restrict__ out){
  const int ot = blockIdx.x >> 6, rest = blockIdx.x & 63;
  const int nt = rest >> 3, b = rest & 7;
  const int o0 = ot*32;
  const int tid = threadIdx.x, wv = tid>>6, lane = tid&63;
  const int l15 = lane&15, quad = lane>>4;
  const int n0w = nt*128 + wv*32;
  __shared__ u16 swp[32][264];
  #pragma unroll
  for (int i = 0; i < 8; i++){                  // fp32 weights -> bf16 LDS
    const int flat = i*256 + tid;
    const int row = flat >> 6, c4 = flat & 63;
    float4 a = *(const float4*)(wp + (size_t)(o0+row)*NC + c4*4);
    uint2 p;
    p.x = (u32)f2b(a.x) | ((u32)f2b(a.y)<<16);
    p.y = (u32)f2b(a.z) | ((u32)f2b(a.w)<<16);
    *(uint2*)&swp[row][c4*4] = p;
  }
  __syncthreads();
  f32x4 acc[2][2];
  #pragma unroll
  for (int mt = 0; mt < 2; mt++)
    #pragma unroll
    for (int n2 = 0; n2 < 2; n2++) acc[mt][n2] = (f32x4){0.f,0.f,0.f,0.f};
  const u16* tb = tt + ((size_t)(b*NN + n0w))*NC;
  for (int k0 = 0; k0 < 256; k0 += 32){
    FR af[2], bf[2];
    af[0].u = *(uint4*)&swp[l15][k0 + quad*8];
    af[1].u = *(uint4*)&swp[16+l15][k0 + quad*8];
    bf[0].u = *(const uint4*)(tb + (size_t)(l15     )*NC + k0 + quad*8);
    bf[1].u = *(const uint4*)(tb + (size_t)(16 + l15)*NC + k0 + quad*8);
    #pragma unroll
    for (int mt = 0; mt < 2; mt++)
      #pragma unroll
      for (int n2 = 0; n2 < 2; n2++)
        acc[mt][n2] = __builtin_amdgcn_mfma_f32_16x16x32_bf16(af[mt].s, bf[n2].s, acc[mt][n2], 0,0,0);
  }
  float bv[2][4];
  #pragma unroll
  for (int mt = 0; mt < 2; mt++)
    #pragma unroll
    for (int r = 0; r < 4; r++) bv[mt][r] = pbias[o0 + mt*16 + quad*4 + r];
  #pragma unroll
  for (int mt = 0; mt < 2; mt++)
    #pragma unroll
    for (int n2 = 0; n2 < 2; n2++)
      #pragma unroll
      for (int r = 0; r < 4; r++)
        out[(size_t)(b*NC + o0 + mt*16 + quad*4 + r)*NN + n0w + n2*16 + l15] = acc[mt][n2][r] + bv[mt][r];
}

extern "C" void kernel_launch(void* const* d_in, const int* in_sizes, int n_in,
                              void* d_out, int out_size, void* d_ws, size_t ws_size,
                              hipStream_t stream){
  const float* x      = (const float*)d_in[0];
  const float* qkv_w  = (const float*)d_in[1];
  const float* proj_w = (const float*)d_in[2];
  const float* proj_b = (const float*)d_in[3];
  const float* lepe_w = (const float*)d_in[4];
  const float* lepe_b = (const float*)d_in[5];
  float* out = (float*)d_out;

  // ws (u16 units): xt 2M | qt 2M | kt 2M | v 2M | tt 2M  (20 MB)
  if (ws_size < (size_t)20*1024*1024) return;
  u16* xt = (u16*)d_ws;
  u16* qt = xt + 2097152;
  u16* kt = qt + 2097152;
  u16* v  = kt + 2097152;
  u16* tt = v  + 2097152;

  k_cast<<<dim3(16, 2, 8), 256, 0, stream>>>(x, xt);
  k_qkv <<<dim3(768),      256, 0, stream>>>(qkv_w, xt, qt, kt, v);
  k_attn<<<dim3(1024),     256, 0, stream>>>(qt, kt, v, lepe_w, lepe_b, tt);
  k_proj<<<dim3(512),      256, 0, stream>>>(proj_w, tt, proj_b, out);
}